// Round 2
// baseline (1203.851 us; speedup 1.0000x reference)
//
#include <hip/hip_runtime.h>
#include <hip/hip_bf16.h>

// ---------------------------------------------------------------------------
// GINE 2-layer GNN, MI355X (gfx950)  — round 2
// Change vs round 1: dst-sorted edge processing (counting sort built per
// launch, reused by both layers) + intra-lane segmented reduction before
// atomicAdd. Cuts device-scope float-atomic dwords ~4x (runs of equal dst,
// avg degree 16, each lane owns 4 consecutive sorted edges).
// ---------------------------------------------------------------------------

typedef short short8 __attribute__((ext_vector_type(8)));
typedef float f32x4 __attribute__((ext_vector_type(4)));

__device__ __forceinline__ short f2bf(float x) {
    unsigned u = __float_as_uint(x);
    unsigned r = (u + 0x7fffu + ((u >> 16) & 1u)) >> 16;   // RTNE
    return (short)r;
}

// ---------------------------------------------------------------------------
// Counting sort of edges by dst
// ---------------------------------------------------------------------------
__global__ __launch_bounds__(256) void hist_kernel(
    const int* __restrict__ ei, int* __restrict__ cnt, int E)
{
    int e = blockIdx.x * 256 + threadIdx.x;
    if (e < E) atomicAdd(&cnt[ei[E + e]], 1);
}

__global__ __launch_bounds__(1024) void scan_kernel(
    const int* __restrict__ cnt, int* __restrict__ offs,
    int* __restrict__ cursor, int N)
{
    __shared__ int wsum[16];
    __shared__ int chunk_base;
    int tid = threadIdx.x;
    int lane = tid & 63, wid = tid >> 6;
    if (tid == 0) chunk_base = 0;
    __syncthreads();
    for (int start = 0; start < N; start += 1024) {
        int i = start + tid;
        int v = (i < N) ? cnt[i] : 0;
        int s = v;
#pragma unroll
        for (int d = 1; d < 64; d <<= 1) {
            int t = __shfl_up(s, d);
            if (lane >= d) s += t;
        }
        if (lane == 63) wsum[wid] = s;
        __syncthreads();
        int wbase = 0;
        for (int w = 0; w < wid; ++w) wbase += wsum[w];
        int excl = chunk_base + wbase + s - v;
        if (i < N) { offs[i] = excl; cursor[i] = excl; }
        int tot = 0;
        for (int w = 0; w < 16; ++w) tot += wsum[w];
        __syncthreads();
        if (tid == 0) chunk_base += tot;
        __syncthreads();
    }
    if (threadIdx.x == 0) offs[N] = chunk_base;
}

__global__ __launch_bounds__(256) void scatter_kernel(
    const int* __restrict__ ei, int* __restrict__ cursor,
    int* __restrict__ perm, int* __restrict__ ssrc, int* __restrict__ sdst,
    int E)
{
    int e = blockIdx.x * 256 + threadIdx.x;
    if (e >= E) return;
    int d = ei[E + e];
    int pos = atomicAdd(&cursor[d], 1);
    perm[pos] = e;
    ssrc[pos] = ei[e];
    sdst[pos] = d;
}

// ---------------------------------------------------------------------------
// Edge kernel (dst-sorted): one wave = 16 sorted edges x D features.
// A-frag rows = sorted edges (gathered via perm); C row (lane>>4)*4+reg maps
// to sorted position ebase+g*4+r -> lane's 4 rows are CONSECUTIVE sorted
// edges -> intra-lane segmented reduce, one atomic per run per lane.
// ---------------------------------------------------------------------------
template<int D>
__global__ __launch_bounds__(256) void edge_kernel_sorted(
    const float* __restrict__ x,      // [N][D]
    const float* __restrict__ eattr,  // [E][64]
    const short* __restrict__ WeB,    // [D][64] bf16
    const float* __restrict__ be,     // [D]
    const int*   __restrict__ perm,   // [E] sorted -> original edge id
    const int*   __restrict__ ssrc,   // [E] src in sorted order
    const int*   __restrict__ sdst,   // [E] dst in sorted order (non-decr)
    float*       __restrict__ agg,    // [N][D]
    int E)
{
    const int wave = threadIdx.x >> 6;
    const int lane = threadIdx.x & 63;
    const int ebase = (blockIdx.x * 4 + wave) * 16;
    if (ebase >= E) return;
    const int g = lane >> 4;        // 0..3
    const int c = lane & 15;        // 0..15

    // --- A fragments: row c = sorted edge ebase+c, k-slice g*8.. ---
    int ap = ebase + c; if (ap >= E) ap = E - 1;
    const float* arow = eattr + (size_t)perm[ap] * 64 + g * 8;
    short8 afr[2];
#pragma unroll
    for (int kt = 0; kt < 2; ++kt) {
        f32x4 a0 = *(const f32x4*)(arow + kt * 32);
        f32x4 a1 = *(const f32x4*)(arow + kt * 32 + 4);
        short8 t;
        t[0] = f2bf(a0[0]); t[1] = f2bf(a0[1]); t[2] = f2bf(a0[2]); t[3] = f2bf(a0[3]);
        t[4] = f2bf(a1[0]); t[5] = f2bf(a1[1]); t[6] = f2bf(a1[2]); t[7] = f2bf(a1[3]);
        afr[kt] = t;
    }

    // --- src/dst for this lane's 4 consecutive sorted edges ---
    int se[4], de[4];
#pragma unroll
    for (int r = 0; r < 4; ++r) {
        int p = ebase + g * 4 + r;
        bool v = p < E;
        int ps = v ? p : (E - 1);
        se[r] = ssrc[ps];
        de[r] = v ? sdst[ps] : -1;
    }

    constexpr int FC = D / 16;
#pragma unroll
    for (int fc = 0; fc < FC; ++fc) {
        const short* brow = WeB + (size_t)(fc * 16 + c) * 64 + g * 8;
        short8 b0 = *(const short8*)(brow);
        short8 b1 = *(const short8*)(brow + 32);
        f32x4 acc = {0.f, 0.f, 0.f, 0.f};
        acc = __builtin_amdgcn_mfma_f32_16x16x32_bf16(afr[0], b0, acc, 0, 0, 0);
        acc = __builtin_amdgcn_mfma_f32_16x16x32_bf16(afr[1], b1, acc, 0, 0, 0);
        const int f = fc * 16 + c;
        const float bev = be[f];
        float m[4];
#pragma unroll
        for (int r = 0; r < 4; ++r) {
            m[r] = (de[r] >= 0)
                 ? fmaxf(acc[r] + bev + x[(size_t)se[r] * D + f], 0.f)
                 : 0.f;
        }
        // segmented flush: merge consecutive rows with equal dst
        float sum = m[0];
#pragma unroll
        for (int r = 1; r < 4; ++r) {
            if (de[r] == de[r - 1]) {
                sum += m[r];
            } else {
                if (de[r - 1] >= 0) atomicAdd(&agg[(size_t)de[r - 1] * D + f], sum);
                sum = m[r];
            }
        }
        if (de[3] >= 0) atomicAdd(&agg[(size_t)de[3] * D + f], sum);
    }
}

// ---------------------------------------------------------------------------
// mlp1: t[n][f] = b1[f] + sum_k (agg[n][k] + x[n][k]) * W1[f][k]
// ---------------------------------------------------------------------------
template<int D>
__global__ __launch_bounds__(256) void mlp1_kernel(
    const float* __restrict__ agg, const float* __restrict__ x,
    const float* __restrict__ W1, const float* __restrict__ b1,
    float* __restrict__ t, int N)
{
    int gid = blockIdx.x * 256 + threadIdx.x;
    int n = gid >> 6, f = gid & 63;
    if (n >= N) return;
    const f32x4* ar = (const f32x4*)(agg + (size_t)n * D);
    const f32x4* xr = (const f32x4*)(x + (size_t)n * D);
    const f32x4* wr = (const f32x4*)(W1 + (size_t)f * D);
    float acc = b1[f];
#pragma unroll
    for (int k = 0; k < D / 4; ++k) {
        f32x4 a = ar[k], xx = xr[k], w = wr[k];
        acc += (a[0] + xx[0]) * w[0] + (a[1] + xx[1]) * w[1]
             + (a[2] + xx[2]) * w[2] + (a[3] + xx[3]) * w[3];
    }
    t[gid] = acc;
}

// ---------------------------------------------------------------------------
// BN stats + final
// ---------------------------------------------------------------------------
__global__ __launch_bounds__(256) void bnstats_kernel(
    const float* __restrict__ t, float* __restrict__ sums, int total)
{
    int tid = threadIdx.x;
    float s = 0.f, s2 = 0.f;
    for (int i = blockIdx.x * 256 + tid; i < total; i += gridDim.x * 256) {
        float v = t[i];
        s += v; s2 += v * v;
    }
    __shared__ float ls[256], ls2[256];
    ls[tid] = s; ls2[tid] = s2;
    __syncthreads();
    if (tid < 64) {
        s  = ls[tid]  + ls[tid + 64]  + ls[tid + 128]  + ls[tid + 192];
        s2 = ls2[tid] + ls2[tid + 64] + ls2[tid + 128] + ls2[tid + 192];
        atomicAdd(&sums[tid], s);
        atomicAdd(&sums[64 + tid], s2);
    }
}

__global__ void bnfinal_kernel(const float* __restrict__ sums,
                               const float* __restrict__ g,
                               const float* __restrict__ bb,
                               float* __restrict__ scsh, float invN)
{
    int f = threadIdx.x;  // 64 threads
    float mean = sums[f] * invN;
    float var  = sums[64 + f] * invN - mean * mean;
    float sc = g[f] * rsqrtf(var + 1e-5f);
    scsh[f] = sc;
    scsh[64 + f] = bb[f] - mean * sc;
}

// ---------------------------------------------------------------------------
// mlp2: h = relu(t*scale+shift); out = h @ W2^T + b2 (+optional relu)
// ---------------------------------------------------------------------------
__global__ __launch_bounds__(256) void mlp2_kernel(
    const float* __restrict__ t, const float* __restrict__ scsh,
    const float* __restrict__ W2, const float* __restrict__ b2,
    float* __restrict__ out, int N, int relu_out)
{
    __shared__ __align__(16) float hs[4][64];
    int tid = threadIdx.x;
    int nl = tid >> 6, k = tid & 63;
    int n = blockIdx.x * 4 + nl;
    float h = 0.f;
    if (n < N) h = fmaxf(t[(size_t)n * 64 + k] * scsh[k] + scsh[64 + k], 0.f);
    hs[nl][k] = h;
    __syncthreads();
    if (n >= N) return;
    const int f = k;
    const f32x4* wr = (const f32x4*)(W2 + (size_t)f * 64);
    const f32x4* hr = (const f32x4*)(hs[nl]);
    float acc = b2[f];
#pragma unroll
    for (int kk = 0; kk < 16; ++kk) {
        f32x4 w = wr[kk], hh = hr[kk];
        acc += hh[0] * w[0] + hh[1] * w[1] + hh[2] * w[2] + hh[3] * w[3];
    }
    if (relu_out) acc = fmaxf(acc, 0.f);
    out[(size_t)n * 64 + f] = acc;
}

// ---------------------------------------------------------------------------
// Weight prep: f32 -> bf16 for We0 (128x64) and We1 (64x64)
// ---------------------------------------------------------------------------
__global__ __launch_bounds__(256) void prep_kernel(
    const float* __restrict__ We0, const float* __restrict__ We1,
    short* __restrict__ WeB0, short* __restrict__ WeB1)
{
    int i = blockIdx.x * 256 + threadIdx.x;
    if (i < 128 * 64) WeB0[i] = f2bf(We0[i]);
    if (i < 64 * 64)  WeB1[i] = f2bf(We1[i]);
}

extern "C" void kernel_launch(void* const* d_in, const int* in_sizes, int n_in,
                              void* d_out, int out_size, void* d_ws, size_t ws_size,
                              hipStream_t stream)
{
    (void)n_in; (void)out_size; (void)ws_size;
    const float* x     = (const float*)d_in[0];
    const int*   ei    = (const int*)d_in[1];
    const float* eattr = (const float*)d_in[2];
    const float* We0   = (const float*)d_in[3];
    const float* be0   = (const float*)d_in[4];
    const float* W1_0  = (const float*)d_in[5];
    const float* b1_0  = (const float*)d_in[6];
    const float* g0    = (const float*)d_in[7];
    const float* bb0   = (const float*)d_in[8];
    const float* W2_0  = (const float*)d_in[9];
    const float* b2_0  = (const float*)d_in[10];
    const float* We1   = (const float*)d_in[11];
    const float* be1   = (const float*)d_in[12];
    const float* W1_1  = (const float*)d_in[13];
    const float* b1_1  = (const float*)d_in[14];
    const float* g1    = (const float*)d_in[15];
    const float* bb1   = (const float*)d_in[16];
    const float* W2_1  = (const float*)d_in[17];
    const float* b2_1  = (const float*)d_in[18];
    float* out = (float*)d_out;

    const int N = in_sizes[0] / 128;   // 50000
    const int E = in_sizes[2] / 64;    // 800000

    char* ws = (char*)d_ws;
    float* agg0 = (float*)ws;                          // N*128 f32
    float* agg1 = (float*)(ws + (size_t)N * 128 * 4);  // N*64 f32
    float* tbuf = agg1 + (size_t)N * 64;               // N*64 f32
    float* y0   = tbuf + (size_t)N * 64;               // N*64 f32
    short* WeB0 = (short*)(y0 + (size_t)N * 64);       // 128*64 bf16
    short* WeB1 = WeB0 + 128 * 64;                     // 64*64 bf16
    float* stats = (float*)(WeB1 + 64 * 64);
    float* sum0  = stats;          // [128] sum+sumsq
    float* scsh0 = stats + 128;    // [128] scale+shift
    float* sum1  = stats + 256;
    float* scsh1 = stats + 384;
    int* cnt    = (int*)(stats + 512);     // [N] counts -> cursor
    int* offs   = cnt + N;                 // [N+1]
    int* perm   = offs + N + 1;            // [E]
    int* ssrc   = perm + E;                // [E]
    int* sdst   = ssrc + E;                // [E]

    hipMemsetAsync(agg0, 0, (size_t)N * 128 * 4, stream);
    hipMemsetAsync(agg1, 0, (size_t)N * 64 * 4, stream);
    hipMemsetAsync(stats, 0, 512 * 4, stream);
    hipMemsetAsync(cnt, 0, (size_t)N * 4, stream);
    prep_kernel<<<32, 256, 0, stream>>>(We0, We1, WeB0, WeB1);

    const int eb256 = (E + 255) / 256;

    // ----- build dst-sorted edge order (shared by both layers) -----
    hist_kernel<<<eb256, 256, 0, stream>>>(ei, cnt, E);
    scan_kernel<<<1, 1024, 0, stream>>>(cnt, offs, cnt, N);  // cnt becomes cursor
    scatter_kernel<<<eb256, 256, 0, stream>>>(ei, cnt, perm, ssrc, sdst, E);

    const int edge_blocks = (E + 63) / 64;
    const int nf_blocks   = (N * 64 + 255) / 256;
    const int n4_blocks   = (N + 3) / 4;

    // ----- layer 0 -----
    edge_kernel_sorted<128><<<edge_blocks, 256, 0, stream>>>(
        x, eattr, WeB0, be0, perm, ssrc, sdst, agg0, E);
    mlp1_kernel<128><<<nf_blocks, 256, 0, stream>>>(agg0, x, W1_0, b1_0, tbuf, N);
    bnstats_kernel<<<256, 256, 0, stream>>>(tbuf, sum0, N * 64);
    bnfinal_kernel<<<1, 64, 0, stream>>>(sum0, g0, bb0, scsh0, 1.0f / N);
    mlp2_kernel<<<n4_blocks, 256, 0, stream>>>(tbuf, scsh0, W2_0, b2_0, y0, N, 1);

    // ----- layer 1 -----
    edge_kernel_sorted<64><<<edge_blocks, 256, 0, stream>>>(
        y0, eattr, WeB1, be1, perm, ssrc, sdst, agg1, E);
    mlp1_kernel<64><<<nf_blocks, 256, 0, stream>>>(agg1, y0, W1_1, b1_1, tbuf, N);
    bnstats_kernel<<<256, 256, 0, stream>>>(tbuf, sum1, N * 64);
    bnfinal_kernel<<<1, 64, 0, stream>>>(sum1, g1, bb1, scsh1, 1.0f / N);
    mlp2_kernel<<<n4_blocks, 256, 0, stream>>>(tbuf, scsh1, W2_1, b2_1, out, N, 0);
}

// Round 3
// 1179.282 us; speedup vs baseline: 1.0208x; 1.0208x over previous
//
#include <hip/hip_runtime.h>
#include <hip/hip_bf16.h>

// ---------------------------------------------------------------------------
// GINE 2-layer GNN, MI355X (gfx950)  — round 3: atomic-free
//   t[n] = sum_{e: dst=n} relu(x[src]+ea_e)@W1^T  +  (x@W1^T + b1)
// edge2_kernel : ea = eattr@We^T (MFMA), m = relu(x[src]+ea+be),
//                LDS transpose (XOR-swizzled), p = m@W1^T (MFMA),
//                write pbuf[e][64] bf16 in ORIGINAL edge order (coalesced).
// gather_kernel: per node, sum pbuf rows via CSR (perm/offs), add xw1.
// xw1_kernel   : dense x@W1^T + b1.
// Then BN-stats / BN-final / mlp2 as before. Counting sort only builds
// perm/offs (dst is never touched in hot kernels). Zero float atomics.
// ---------------------------------------------------------------------------

typedef short short8 __attribute__((ext_vector_type(8)));
typedef float f32x4 __attribute__((ext_vector_type(4)));

__device__ __forceinline__ short f2bf(float x) {
    unsigned u = __float_as_uint(x);
    unsigned r = (u + 0x7fffu + ((u >> 16) & 1u)) >> 16;   // RTNE
    return (short)r;
}
__device__ __forceinline__ float bf2f(unsigned short u) {
    return __uint_as_float(((unsigned)u) << 16);
}

// ---------------------------------------------------------------------------
// Counting sort of edges by dst -> perm (sorted pos -> edge id), offs (CSR)
// ---------------------------------------------------------------------------
__global__ __launch_bounds__(256) void hist_kernel(
    const int* __restrict__ ei, int* __restrict__ cnt, int E)
{
    int e = blockIdx.x * 256 + threadIdx.x;
    if (e < E) atomicAdd(&cnt[ei[E + e]], 1);
}

__global__ __launch_bounds__(1024) void scan_kernel(
    const int* __restrict__ cnt, int* __restrict__ offs,
    int* __restrict__ cursor, int N)
{
    __shared__ int wsum[16];
    __shared__ int chunk_base;
    int tid = threadIdx.x;
    int lane = tid & 63, wid = tid >> 6;
    if (tid == 0) chunk_base = 0;
    __syncthreads();
    for (int start = 0; start < N; start += 1024) {
        int i = start + tid;
        int v = (i < N) ? cnt[i] : 0;
        int s = v;
#pragma unroll
        for (int d = 1; d < 64; d <<= 1) {
            int t = __shfl_up(s, d);
            if (lane >= d) s += t;
        }
        if (lane == 63) wsum[wid] = s;
        __syncthreads();
        int wbase = 0;
        for (int w = 0; w < wid; ++w) wbase += wsum[w];
        int excl = chunk_base + wbase + s - v;
        if (i < N) { offs[i] = excl; cursor[i] = excl; }
        int tot = 0;
        for (int w = 0; w < 16; ++w) tot += wsum[w];
        __syncthreads();
        if (tid == 0) chunk_base += tot;
        __syncthreads();
    }
    if (threadIdx.x == 0) offs[N] = chunk_base;
}

__global__ __launch_bounds__(256) void scatter_kernel(
    const int* __restrict__ ei, int* __restrict__ cursor,
    int* __restrict__ perm, int E)
{
    int e = blockIdx.x * 256 + threadIdx.x;
    if (e >= E) return;
    int d = ei[E + e];
    int pos = atomicAdd(&cursor[d], 1);
    perm[pos] = e;
}

// ---------------------------------------------------------------------------
// Edge kernel: wave = 16 edges (original order).
// GEMM1: ea[16 x DIN] = eattr[16 x 64] @ We^T       (C: col=feat, row=edge)
// epilogue: m = relu(ea + be + x[src])  -> LDS tile [16][DIN+4], XOR-swizzled
// GEMM2: p[16 x 64] = m[16 x DIN] @ W1^T            (A-frags read from LDS)
// write pbuf[e][64] bf16.
// ---------------------------------------------------------------------------
template<int DIN>
__global__ __launch_bounds__(256) void edge2_kernel(
    const float*  __restrict__ x,      // [N][DIN] (node features, relu'd)
    const int*    __restrict__ ei,     // [2][E] (src row used)
    const float*  __restrict__ eattr,  // [E][64]
    const short*  __restrict__ WeB,    // [DIN][64] bf16
    const float*  __restrict__ be,     // [DIN]
    const short*  __restrict__ W1B,    // [64][DIN] bf16
    unsigned short* __restrict__ pbuf, // [E][64] bf16
    int E)
{
    constexpr int LDW = DIN + 4;           // dword row stride (16B aligned)
    __shared__ float lds[4][16][LDW];
    const int wave = threadIdx.x >> 6;
    const int lane = threadIdx.x & 63;
    const int ebase = (blockIdx.x * 4 + wave) * 16;
    if (ebase >= E) return;
    const int g = lane >> 4;               // 0..3 (k-slice / row-group)
    const int c = lane & 15;               // 0..15 (col / row-in-tile)
    float* myl = &lds[wave][0][0];

    // --- A fragments from eattr (streaming, original order) ---
    int arow_e = ebase + c; if (arow_e >= E) arow_e = E - 1;
    const float* arow = eattr + (size_t)arow_e * 64 + g * 8;
    short8 afr[2];
#pragma unroll
    for (int kt = 0; kt < 2; ++kt) {
        f32x4 a0 = *(const f32x4*)(arow + kt * 32);
        f32x4 a1 = *(const f32x4*)(arow + kt * 32 + 4);
        short8 t;
        t[0] = f2bf(a0[0]); t[1] = f2bf(a0[1]); t[2] = f2bf(a0[2]); t[3] = f2bf(a0[3]);
        t[4] = f2bf(a1[0]); t[5] = f2bf(a1[1]); t[6] = f2bf(a1[2]); t[7] = f2bf(a1[3]);
        afr[kt] = t;
    }

    // --- src nodes for this lane's 4 C-rows ---
    int se[4];
#pragma unroll
    for (int r = 0; r < 4; ++r) {
        int e = ebase + g * 4 + r;
        se[r] = ei[(e < E) ? e : (E - 1)];
    }

    // --- GEMM1 + epilogue -> LDS (XOR swizzle: f' = f ^ (r<<3)) ---
    constexpr int FC = DIN / 16;
#pragma unroll
    for (int fc = 0; fc < FC; ++fc) {
        const short* brow = WeB + (size_t)(fc * 16 + c) * 64 + g * 8;
        short8 b0 = *(const short8*)(brow);
        short8 b1 = *(const short8*)(brow + 32);
        f32x4 acc = {0.f, 0.f, 0.f, 0.f};
        acc = __builtin_amdgcn_mfma_f32_16x16x32_bf16(afr[0], b0, acc, 0, 0, 0);
        acc = __builtin_amdgcn_mfma_f32_16x16x32_bf16(afr[1], b1, acc, 0, 0, 0);
        const int f = fc * 16 + c;
        const float bev = be[f];
#pragma unroll
        for (int r = 0; r < 4; ++r) {
            float m = fmaxf(acc[r] + bev + x[(size_t)se[r] * DIN + f], 0.f);
            myl[(g * 4 + r) * LDW + (f ^ (r << 3))] = m;
        }
    }

    // producer->consumer fence (same wave, different lanes' LDS data)
    asm volatile("s_waitcnt lgkmcnt(0)" ::: "memory");
    __builtin_amdgcn_sched_barrier(0);

    // --- A2 fragments: row = c (edge), k-slice = kk*32 + g*8 (un-swizzle) ---
    constexpr int KK = DIN / 32;
    short8 a2[KK];
#pragma unroll
    for (int kk = 0; kk < KK; ++kk) {
        int off = c * LDW + ((kk * 32 + g * 8) ^ ((c & 3) << 3));
        f32x4 q0 = *(const f32x4*)(myl + off);
        f32x4 q1 = *(const f32x4*)(myl + off + 4);
        short8 t;
        t[0] = f2bf(q0[0]); t[1] = f2bf(q0[1]); t[2] = f2bf(q0[2]); t[3] = f2bf(q0[3]);
        t[4] = f2bf(q1[0]); t[5] = f2bf(q1[1]); t[6] = f2bf(q1[2]); t[7] = f2bf(q1[3]);
        a2[kk] = t;
    }

    // --- GEMM2: p = m @ W1^T ; write bf16 (guarded) ---
#pragma unroll
    for (int cc = 0; cc < 4; ++cc) {
        f32x4 acc2 = {0.f, 0.f, 0.f, 0.f};
#pragma unroll
        for (int kk = 0; kk < KK; ++kk) {
            const short* brow = W1B + (size_t)(cc * 16 + c) * DIN + kk * 32 + g * 8;
            short8 b0 = *(const short8*)(brow);
            acc2 = __builtin_amdgcn_mfma_f32_16x16x32_bf16(a2[kk], b0, acc2, 0, 0, 0);
        }
#pragma unroll
        for (int r = 0; r < 4; ++r) {
            int e = ebase + g * 4 + r;
            if (e < E) pbuf[(size_t)e * 64 + cc * 16 + c] = (unsigned short)f2bf(acc2[r]);
        }
    }
}

// ---------------------------------------------------------------------------
// xw1: xw1[n][f] = b1[f] + sum_k x[n][k] * W1[f][k]    (dense, f32)
// ---------------------------------------------------------------------------
template<int DIN>
__global__ __launch_bounds__(256) void xw1_kernel(
    const float* __restrict__ x, const float* __restrict__ W1,
    const float* __restrict__ b1, float* __restrict__ xw1, int N)
{
    int gid = blockIdx.x * 256 + threadIdx.x;
    int n = gid >> 6, f = gid & 63;
    if (n >= N) return;
    const f32x4* xr = (const f32x4*)(x + (size_t)n * DIN);
    const f32x4* wr = (const f32x4*)(W1 + (size_t)f * DIN);
    float acc = b1[f];
#pragma unroll
    for (int k = 0; k < DIN / 4; ++k) {
        f32x4 xx = xr[k], w = wr[k];
        acc += xx[0] * w[0] + xx[1] * w[1] + xx[2] * w[2] + xx[3] * w[3];
    }
    xw1[gid] = acc;
}

// ---------------------------------------------------------------------------
// gather: t[n][f] = xw1[n][f] + sum_{i in [offs[n],offs[n+1])} pbuf[perm[i]][f]
// wave per node; lane = feature; 128B coalesced row reads; 2-deep unroll.
// ---------------------------------------------------------------------------
__global__ __launch_bounds__(256) void gather_kernel(
    const unsigned short* __restrict__ pbuf,
    const int* __restrict__ perm, const int* __restrict__ offs,
    const float* __restrict__ xw1, float* __restrict__ t, int N)
{
    int wid = threadIdx.x >> 6, lane = threadIdx.x & 63;
    int n = blockIdx.x * 4 + wid;
    if (n >= N) return;
    int i0 = offs[n], i1 = offs[n + 1];
    float s = 0.f;
    int i = i0;
    for (; i + 1 < i1; i += 2) {
        int e0 = perm[i], e1 = perm[i + 1];
        unsigned short u0 = pbuf[(size_t)e0 * 64 + lane];
        unsigned short u1 = pbuf[(size_t)e1 * 64 + lane];
        s += bf2f(u0) + bf2f(u1);
    }
    if (i < i1) {
        int e0 = perm[i];
        s += bf2f(pbuf[(size_t)e0 * 64 + lane]);
    }
    t[(size_t)n * 64 + lane] = s + xw1[(size_t)n * 64 + lane];
}

// ---------------------------------------------------------------------------
// BN stats + final
// ---------------------------------------------------------------------------
__global__ __launch_bounds__(256) void bnstats_kernel(
    const float* __restrict__ t, float* __restrict__ sums, int total)
{
    int tid = threadIdx.x;
    float s = 0.f, s2 = 0.f;
    for (int i = blockIdx.x * 256 + tid; i < total; i += gridDim.x * 256) {
        float v = t[i];
        s += v; s2 += v * v;
    }
    __shared__ float ls[256], ls2[256];
    ls[tid] = s; ls2[tid] = s2;
    __syncthreads();
    if (tid < 64) {
        s  = ls[tid]  + ls[tid + 64]  + ls[tid + 128]  + ls[tid + 192];
        s2 = ls2[tid] + ls2[tid + 64] + ls2[tid + 128] + ls2[tid + 192];
        atomicAdd(&sums[tid], s);
        atomicAdd(&sums[64 + tid], s2);
    }
}

__global__ void bnfinal_kernel(const float* __restrict__ sums,
                               const float* __restrict__ g,
                               const float* __restrict__ bb,
                               float* __restrict__ scsh, float invN)
{
    int f = threadIdx.x;  // 64 threads
    float mean = sums[f] * invN;
    float var  = sums[64 + f] * invN - mean * mean;
    float sc = g[f] * rsqrtf(var + 1e-5f);
    scsh[f] = sc;
    scsh[64 + f] = bb[f] - mean * sc;
}

// ---------------------------------------------------------------------------
// mlp2: h = relu(t*scale+shift); out = h @ W2^T + b2 (+optional relu)
// ---------------------------------------------------------------------------
__global__ __launch_bounds__(256) void mlp2_kernel(
    const float* __restrict__ t, const float* __restrict__ scsh,
    const float* __restrict__ W2, const float* __restrict__ b2,
    float* __restrict__ out, int N, int relu_out)
{
    __shared__ __align__(16) float hs[4][64];
    int tid = threadIdx.x;
    int nl = tid >> 6, k = tid & 63;
    int n = blockIdx.x * 4 + nl;
    float h = 0.f;
    if (n < N) h = fmaxf(t[(size_t)n * 64 + k] * scsh[k] + scsh[64 + k], 0.f);
    hs[nl][k] = h;
    __syncthreads();
    if (n >= N) return;
    const int f = k;
    const f32x4* wr = (const f32x4*)(W2 + (size_t)f * 64);
    const f32x4* hr = (const f32x4*)(hs[nl]);
    float acc = b2[f];
#pragma unroll
    for (int kk = 0; kk < 16; ++kk) {
        f32x4 w = wr[kk], hh = hr[kk];
        acc += hh[0] * w[0] + hh[1] * w[1] + hh[2] * w[2] + hh[3] * w[3];
    }
    if (relu_out) acc = fmaxf(acc, 0.f);
    out[(size_t)n * 64 + f] = acc;
}

// ---------------------------------------------------------------------------
// Weight prep: f32 -> bf16 (WeB0 128x64, W1B0 64x128, WeB1 64x64, W1B1 64x64)
// ---------------------------------------------------------------------------
__global__ __launch_bounds__(256) void prep_kernel(
    const float* __restrict__ We0, const float* __restrict__ W1_0,
    const float* __restrict__ We1, const float* __restrict__ W1_1,
    short* __restrict__ WeB0, short* __restrict__ W1B0,
    short* __restrict__ WeB1, short* __restrict__ W1B1)
{
    int i = blockIdx.x * 256 + threadIdx.x;
    if (i < 128 * 64) WeB0[i] = f2bf(We0[i]);
    if (i < 64 * 128) W1B0[i] = f2bf(W1_0[i]);
    if (i < 64 * 64)  WeB1[i] = f2bf(We1[i]);
    if (i < 64 * 64)  W1B1[i] = f2bf(W1_1[i]);
}

extern "C" void kernel_launch(void* const* d_in, const int* in_sizes, int n_in,
                              void* d_out, int out_size, void* d_ws, size_t ws_size,
                              hipStream_t stream)
{
    (void)n_in; (void)out_size; (void)ws_size;
    const float* x     = (const float*)d_in[0];
    const int*   ei    = (const int*)d_in[1];
    const float* eattr = (const float*)d_in[2];
    const float* We0   = (const float*)d_in[3];
    const float* be0   = (const float*)d_in[4];
    const float* W1_0  = (const float*)d_in[5];
    const float* b1_0  = (const float*)d_in[6];
    const float* g0    = (const float*)d_in[7];
    const float* bb0   = (const float*)d_in[8];
    const float* W2_0  = (const float*)d_in[9];
    const float* b2_0  = (const float*)d_in[10];
    const float* We1   = (const float*)d_in[11];
    const float* be1   = (const float*)d_in[12];
    const float* W1_1  = (const float*)d_in[13];
    const float* b1_1  = (const float*)d_in[14];
    const float* g1    = (const float*)d_in[15];
    const float* bb1   = (const float*)d_in[16];
    const float* W2_1  = (const float*)d_in[17];
    const float* b2_1  = (const float*)d_in[18];
    float* out = (float*)d_out;

    const int N = in_sizes[0] / 128;   // 50000
    const int E = in_sizes[2] / 64;    // 800000

    char* ws = (char*)d_ws;
    size_t o = 0;
    auto alloc = [&](size_t bytes) { char* p = ws + o; o = (o + bytes + 255) & ~(size_t)255; return p; };
    unsigned short* pbuf = (unsigned short*)alloc((size_t)E * 64 * 2);
    float* tbuf   = (float*)alloc((size_t)N * 64 * 4);
    float* y0     = (float*)alloc((size_t)N * 64 * 4);
    float* xw1buf = (float*)alloc((size_t)N * 64 * 4);
    short* WeB0   = (short*)alloc(128 * 64 * 2);
    short* W1B0   = (short*)alloc(64 * 128 * 2);
    short* WeB1   = (short*)alloc(64 * 64 * 2);
    short* W1B1   = (short*)alloc(64 * 64 * 2);
    float* stats  = (float*)alloc(512 * 4);
    int*   cnt    = (int*)alloc((size_t)N * 4);
    int*   offs   = (int*)alloc((size_t)(N + 1) * 4);
    int*   perm   = (int*)alloc((size_t)E * 4);
    float* sum0  = stats;          // [128] sum+sumsq
    float* scsh0 = stats + 128;    // [128] scale+shift
    float* sum1  = stats + 256;
    float* scsh1 = stats + 384;

    hipMemsetAsync(stats, 0, 512 * 4, stream);
    hipMemsetAsync(cnt, 0, (size_t)N * 4, stream);
    prep_kernel<<<96, 256, 0, stream>>>(We0, W1_0, We1, W1_1, WeB0, W1B0, WeB1, W1B1);

    const int eb256 = (E + 255) / 256;

    // ----- build CSR (perm/offs) by dst; shared by both layers -----
    hist_kernel<<<eb256, 256, 0, stream>>>(ei, cnt, E);
    scan_kernel<<<1, 1024, 0, stream>>>(cnt, offs, cnt, N);  // cnt becomes cursor
    scatter_kernel<<<eb256, 256, 0, stream>>>(ei, cnt, perm, E);

    const int edge_blocks = (E + 63) / 64;
    const int nf_blocks   = (N * 64 + 255) / 256;
    const int n4_blocks   = (N + 3) / 4;

    // ----- layer 0 -----
    edge2_kernel<128><<<edge_blocks, 256, 0, stream>>>(
        x, ei, eattr, WeB0, be0, W1B0, pbuf, E);
    xw1_kernel<128><<<nf_blocks, 256, 0, stream>>>(x, W1_0, b1_0, xw1buf, N);
    gather_kernel<<<n4_blocks, 256, 0, stream>>>(pbuf, perm, offs, xw1buf, tbuf, N);
    bnstats_kernel<<<256, 256, 0, stream>>>(tbuf, sum0, N * 64);
    bnfinal_kernel<<<1, 64, 0, stream>>>(sum0, g0, bb0, scsh0, 1.0f / N);
    mlp2_kernel<<<n4_blocks, 256, 0, stream>>>(tbuf, scsh0, W2_0, b2_0, y0, N, 1);

    // ----- layer 1 -----
    edge2_kernel<64><<<edge_blocks, 256, 0, stream>>>(
        y0, ei, eattr, WeB1, be1, W1B1, pbuf, E);
    xw1_kernel<64><<<nf_blocks, 256, 0, stream>>>(y0, W1_1, b1_1, xw1buf, N);
    gather_kernel<<<n4_blocks, 256, 0, stream>>>(pbuf, perm, offs, xw1buf, tbuf, N);
    bnstats_kernel<<<256, 256, 0, stream>>>(tbuf, sum1, N * 64);
    bnfinal_kernel<<<1, 64, 0, stream>>>(sum1, g1, bb1, scsh1, 1.0f / N);
    mlp2_kernel<<<n4_blocks, 256, 0, stream>>>(tbuf, scsh1, W2_1, b2_1, out, N, 0);
}

// Round 4
// 1092.839 us; speedup vs baseline: 1.1016x; 1.0791x over previous
//
#include <hip/hip_runtime.h>
#include <hip/hip_bf16.h>

// ---------------------------------------------------------------------------
// GINE 2-layer GNN, MI355X (gfx950)  — round 4
//   t[n] = sum_{e: dst=n} relu(x[src]+ea_e)@W1^T  +  (x@W1^T + b1)
// Changes vs R3 (latency/occupancy-bound at 40% occ):
//  1. bf16 LDS transpose tile, stride DIN+8 shorts -> LDS/block halved
//     (33792 -> 17408 B), occupancy cap 4 -> 8 blocks/CU; single f2bf.
//  2. pbuf written at dst-sorted position (inv_perm) -> gather reads are
//     contiguous streams, no perm indirection.
//  3. xw1 fused into gather (lane=f dot x[n].W1[f], weights L1-resident).
// ---------------------------------------------------------------------------

typedef short short8 __attribute__((ext_vector_type(8)));
typedef float f32x4 __attribute__((ext_vector_type(4)));

__device__ __forceinline__ short f2bf(float x) {
    unsigned u = __float_as_uint(x);
    unsigned r = (u + 0x7fffu + ((u >> 16) & 1u)) >> 16;   // RTNE
    return (short)r;
}
__device__ __forceinline__ float bf2f(unsigned short u) {
    return __uint_as_float(((unsigned)u) << 16);
}

// ---------------------------------------------------------------------------
// Counting sort of edges by dst -> inv (edge id -> sorted pos), offs (CSR)
// ---------------------------------------------------------------------------
__global__ __launch_bounds__(256) void hist_kernel(
    const int* __restrict__ ei, int* __restrict__ cnt, int E)
{
    int e = blockIdx.x * 256 + threadIdx.x;
    if (e < E) atomicAdd(&cnt[ei[E + e]], 1);
}

__global__ __launch_bounds__(1024) void scan_kernel(
    const int* __restrict__ cnt, int* __restrict__ offs,
    int* __restrict__ cursor, int N)
{
    __shared__ int wsum[16];
    __shared__ int chunk_base;
    int tid = threadIdx.x;
    int lane = tid & 63, wid = tid >> 6;
    if (tid == 0) chunk_base = 0;
    __syncthreads();
    for (int start = 0; start < N; start += 1024) {
        int i = start + tid;
        int v = (i < N) ? cnt[i] : 0;
        int s = v;
#pragma unroll
        for (int d = 1; d < 64; d <<= 1) {
            int t = __shfl_up(s, d);
            if (lane >= d) s += t;
        }
        if (lane == 63) wsum[wid] = s;
        __syncthreads();
        int wbase = 0;
        for (int w = 0; w < wid; ++w) wbase += wsum[w];
        int excl = chunk_base + wbase + s - v;
        if (i < N) { offs[i] = excl; cursor[i] = excl; }
        int tot = 0;
        for (int w = 0; w < 16; ++w) tot += wsum[w];
        __syncthreads();
        if (tid == 0) chunk_base += tot;
        __syncthreads();
    }
    if (threadIdx.x == 0) offs[N] = chunk_base;
}

__global__ __launch_bounds__(256) void scatter_kernel(
    const int* __restrict__ ei, int* __restrict__ cursor,
    int* __restrict__ inv, int E)
{
    int e = blockIdx.x * 256 + threadIdx.x;
    if (e >= E) return;
    int d = ei[E + e];
    int pos = atomicAdd(&cursor[d], 1);
    inv[e] = pos;
}

// ---------------------------------------------------------------------------
// Edge kernel: wave = 16 edges (original order).
// GEMM1: ea[16 x DIN] = eattr[16 x 64] @ We^T   (C: col=feat c, row=g*4+r)
// epilogue: m = relu(ea + be + x[src]) -> bf16 LDS tile [16][S], S=DIN+8
// GEMM2: p[16 x 64] = m @ W1^T  (A2 frags = short8 straight from LDS)
// store p bf16 at dst-sorted row inv[e]  -> gather reads contiguously.
// ---------------------------------------------------------------------------
template<int DIN>
__global__ __launch_bounds__(256) void edge2_kernel(
    const float*  __restrict__ x,      // [N][DIN]
    const int*    __restrict__ ei,     // [2][E] (src row used)
    const float*  __restrict__ eattr,  // [E][64]
    const short*  __restrict__ WeB,    // [DIN][64] bf16
    const float*  __restrict__ be,     // [DIN]
    const short*  __restrict__ W1B,    // [64][DIN] bf16
    const int*    __restrict__ inv,    // [E] edge -> sorted pos
    unsigned short* __restrict__ pbuf, // [E][64] bf16 (sorted rows)
    int E)
{
    constexpr int S = DIN + 8;             // shorts; rows 16B-aligned
    __shared__ short lds[4][16][S];
    const int wave = threadIdx.x >> 6;
    const int lane = threadIdx.x & 63;
    const int ebase = (blockIdx.x * 4 + wave) * 16;
    if (ebase >= E) return;
    const int g = lane >> 4;               // 0..3
    const int c = lane & 15;               // 0..15
    short* myl = &lds[wave][0][0];

    // --- A fragments from eattr (streaming, original order) ---
    int arow_e = ebase + c; if (arow_e >= E) arow_e = E - 1;
    const float* arow = eattr + (size_t)arow_e * 64 + g * 8;
    short8 afr[2];
#pragma unroll
    for (int kt = 0; kt < 2; ++kt) {
        f32x4 a0 = *(const f32x4*)(arow + kt * 32);
        f32x4 a1 = *(const f32x4*)(arow + kt * 32 + 4);
        short8 t;
        t[0] = f2bf(a0[0]); t[1] = f2bf(a0[1]); t[2] = f2bf(a0[2]); t[3] = f2bf(a0[3]);
        t[4] = f2bf(a1[0]); t[5] = f2bf(a1[1]); t[6] = f2bf(a1[2]); t[7] = f2bf(a1[3]);
        afr[kt] = t;
    }

    // --- src nodes + sorted positions for this lane's 4 C-rows ---
    int se[4], sp[4];
#pragma unroll
    for (int r = 0; r < 4; ++r) {
        int e = ebase + g * 4 + r;
        int es = (e < E) ? e : (E - 1);
        se[r] = ei[es];
        sp[r] = (e < E) ? inv[e] : -1;
    }

    // --- GEMM1 + epilogue -> bf16 LDS ---
    constexpr int FC = DIN / 16;
#pragma unroll
    for (int fc = 0; fc < FC; ++fc) {
        const short* brow = WeB + (size_t)(fc * 16 + c) * 64 + g * 8;
        short8 b0 = *(const short8*)(brow);
        short8 b1 = *(const short8*)(brow + 32);
        f32x4 acc = {0.f, 0.f, 0.f, 0.f};
        acc = __builtin_amdgcn_mfma_f32_16x16x32_bf16(afr[0], b0, acc, 0, 0, 0);
        acc = __builtin_amdgcn_mfma_f32_16x16x32_bf16(afr[1], b1, acc, 0, 0, 0);
        const int f = fc * 16 + c;
        const float bev = be[f];
#pragma unroll
        for (int r = 0; r < 4; ++r) {
            float m = fmaxf(acc[r] + bev + x[(size_t)se[r] * DIN + f], 0.f);
            myl[(g * 4 + r) * S + f] = f2bf(m);
        }
    }

    // producer->consumer fence (cross-lane LDS within the wave)
    asm volatile("s_waitcnt lgkmcnt(0)" ::: "memory");
    __builtin_amdgcn_sched_barrier(0);

    // --- A2 fragments: row = c, k-slice kk*32+g*8 ; bf16 direct ---
    constexpr int KK = DIN / 32;
    short8 a2[KK];
#pragma unroll
    for (int kk = 0; kk < KK; ++kk)
        a2[kk] = *(const short8*)(myl + c * S + kk * 32 + g * 8);

    // --- GEMM2: p = m @ W1^T ; store bf16 at sorted row ---
#pragma unroll
    for (int cc = 0; cc < 4; ++cc) {
        f32x4 acc2 = {0.f, 0.f, 0.f, 0.f};
#pragma unroll
        for (int kk = 0; kk < KK; ++kk) {
            const short* brow = W1B + (size_t)(cc * 16 + c) * DIN + kk * 32 + g * 8;
            short8 b0 = *(const short8*)(brow);
            acc2 = __builtin_amdgcn_mfma_f32_16x16x32_bf16(a2[kk], b0, acc2, 0, 0, 0);
        }
#pragma unroll
        for (int r = 0; r < 4; ++r) {
            if (sp[r] >= 0)
                pbuf[(size_t)sp[r] * 64 + cc * 16 + c] = (unsigned short)f2bf(acc2[r]);
        }
    }
}

// ---------------------------------------------------------------------------
// gather (fused xw1): wave per node, lane = out feature f.
//   t[n][f] = b1[f] + x[n].W1[f] + sum_{i in [offs[n],offs[n+1])} pbuf[i][f]
// pbuf rows for node n are CONTIGUOUS (sorted layout) -> streaming reads.
// ---------------------------------------------------------------------------
template<int DIN>
__global__ __launch_bounds__(256) void gather_kernel(
    const unsigned short* __restrict__ pbuf,
    const int* __restrict__ offs,
    const float* __restrict__ x, const float* __restrict__ W1,
    const float* __restrict__ b1, float* __restrict__ t, int N)
{
    int wid = threadIdx.x >> 6, lane = threadIdx.x & 63;
    int n = blockIdx.x * 4 + wid;
    if (n >= N) return;

    // dense term: x[n] . W1[lane]
    const f32x4* xr = (const f32x4*)(x + (size_t)n * DIN);
    const f32x4* wr = (const f32x4*)(W1 + (size_t)lane * DIN);
    float acc = b1[lane];
#pragma unroll
    for (int k = 0; k < DIN / 4; ++k) {
        f32x4 xx = xr[k], w = wr[k];
        acc += xx[0] * w[0] + xx[1] * w[1] + xx[2] * w[2] + xx[3] * w[3];
    }

    // edge term: contiguous rows
    int i0 = offs[n], i1 = offs[n + 1];
    const unsigned short* p = pbuf + (size_t)i0 * 64 + lane;
    int cnt = i1 - i0;
    int i = 0;
    for (; i + 3 < cnt; i += 4) {
        acc += bf2f(p[0]) + bf2f(p[64]) + bf2f(p[128]) + bf2f(p[192]);
        p += 256;
    }
    for (; i < cnt; ++i) { acc += bf2f(p[0]); p += 64; }
    t[(size_t)n * 64 + lane] = acc;
}

// ---------------------------------------------------------------------------
// BN stats + final
// ---------------------------------------------------------------------------
__global__ __launch_bounds__(256) void bnstats_kernel(
    const float* __restrict__ t, float* __restrict__ sums, int total)
{
    int tid = threadIdx.x;
    float s = 0.f, s2 = 0.f;
    for (int i = blockIdx.x * 256 + tid; i < total; i += gridDim.x * 256) {
        float v = t[i];
        s += v; s2 += v * v;
    }
    __shared__ float ls[256], ls2[256];
    ls[tid] = s; ls2[tid] = s2;
    __syncthreads();
    if (tid < 64) {
        s  = ls[tid]  + ls[tid + 64]  + ls[tid + 128]  + ls[tid + 192];
        s2 = ls2[tid] + ls2[tid + 64] + ls2[tid + 128] + ls2[tid + 192];
        atomicAdd(&sums[tid], s);
        atomicAdd(&sums[64 + tid], s2);
    }
}

__global__ void bnfinal_kernel(const float* __restrict__ sums,
                               const float* __restrict__ g,
                               const float* __restrict__ bb,
                               float* __restrict__ scsh, float invN)
{
    int f = threadIdx.x;  // 64 threads
    float mean = sums[f] * invN;
    float var  = sums[64 + f] * invN - mean * mean;
    float sc = g[f] * rsqrtf(var + 1e-5f);
    scsh[f] = sc;
    scsh[64 + f] = bb[f] - mean * sc;
}

// ---------------------------------------------------------------------------
// mlp2: h = relu(t*scale+shift); out = h @ W2^T + b2 (+optional relu)
// ---------------------------------------------------------------------------
__global__ __launch_bounds__(256) void mlp2_kernel(
    const float* __restrict__ t, const float* __restrict__ scsh,
    const float* __restrict__ W2, const float* __restrict__ b2,
    float* __restrict__ out, int N, int relu_out)
{
    __shared__ __align__(16) float hs[4][64];
    int tid = threadIdx.x;
    int nl = tid >> 6, k = tid & 63;
    int n = blockIdx.x * 4 + nl;
    float h = 0.f;
    if (n < N) h = fmaxf(t[(size_t)n * 64 + k] * scsh[k] + scsh[64 + k], 0.f);
    hs[nl][k] = h;
    __syncthreads();
    if (n >= N) return;
    const int f = k;
    const f32x4* wr = (const f32x4*)(W2 + (size_t)f * 64);
    const f32x4* hr = (const f32x4*)(hs[nl]);
    float acc = b2[f];
#pragma unroll
    for (int kk = 0; kk < 16; ++kk) {
        f32x4 w = wr[kk], hh = hr[kk];
        acc += hh[0] * w[0] + hh[1] * w[1] + hh[2] * w[2] + hh[3] * w[3];
    }
    if (relu_out) acc = fmaxf(acc, 0.f);
    out[(size_t)n * 64 + f] = acc;
}

// ---------------------------------------------------------------------------
// Weight prep: f32 -> bf16
// ---------------------------------------------------------------------------
__global__ __launch_bounds__(256) void prep_kernel(
    const float* __restrict__ We0, const float* __restrict__ W1_0,
    const float* __restrict__ We1, const float* __restrict__ W1_1,
    short* __restrict__ WeB0, short* __restrict__ W1B0,
    short* __restrict__ WeB1, short* __restrict__ W1B1)
{
    int i = blockIdx.x * 256 + threadIdx.x;
    if (i < 128 * 64) WeB0[i] = f2bf(We0[i]);
    if (i < 64 * 128) W1B0[i] = f2bf(W1_0[i]);
    if (i < 64 * 64)  WeB1[i] = f2bf(We1[i]);
    if (i < 64 * 64)  W1B1[i] = f2bf(W1_1[i]);
}

extern "C" void kernel_launch(void* const* d_in, const int* in_sizes, int n_in,
                              void* d_out, int out_size, void* d_ws, size_t ws_size,
                              hipStream_t stream)
{
    (void)n_in; (void)out_size; (void)ws_size;
    const float* x     = (const float*)d_in[0];
    const int*   ei    = (const int*)d_in[1];
    const float* eattr = (const float*)d_in[2];
    const float* We0   = (const float*)d_in[3];
    const float* be0   = (const float*)d_in[4];
    const float* W1_0  = (const float*)d_in[5];
    const float* b1_0  = (const float*)d_in[6];
    const float* g0    = (const float*)d_in[7];
    const float* bb0   = (const float*)d_in[8];
    const float* W2_0  = (const float*)d_in[9];
    const float* b2_0  = (const float*)d_in[10];
    const float* We1   = (const float*)d_in[11];
    const float* be1   = (const float*)d_in[12];
    const float* W1_1  = (const float*)d_in[13];
    const float* b1_1  = (const float*)d_in[14];
    const float* g1    = (const float*)d_in[15];
    const float* bb1   = (const float*)d_in[16];
    const float* W2_1  = (const float*)d_in[17];
    const float* b2_1  = (const float*)d_in[18];
    float* out = (float*)d_out;

    const int N = in_sizes[0] / 128;   // 50000
    const int E = in_sizes[2] / 64;    // 800000

    char* ws = (char*)d_ws;
    size_t o = 0;
    auto alloc = [&](size_t bytes) { char* p = ws + o; o = (o + bytes + 255) & ~(size_t)255; return p; };
    unsigned short* pbuf = (unsigned short*)alloc((size_t)E * 64 * 2);
    float* tbuf   = (float*)alloc((size_t)N * 64 * 4);
    float* y0     = (float*)alloc((size_t)N * 64 * 4);
    short* WeB0   = (short*)alloc(128 * 64 * 2);
    short* W1B0   = (short*)alloc(64 * 128 * 2);
    short* WeB1   = (short*)alloc(64 * 64 * 2);
    short* W1B1   = (short*)alloc(64 * 64 * 2);
    float* stats  = (float*)alloc(512 * 4);
    int*   cnt    = (int*)alloc((size_t)N * 4);
    int*   offs   = (int*)alloc((size_t)(N + 1) * 4);
    int*   inv    = (int*)alloc((size_t)E * 4);
    float* sum0  = stats;          // [128] sum+sumsq
    float* scsh0 = stats + 128;    // [128] scale+shift
    float* sum1  = stats + 256;
    float* scsh1 = stats + 384;

    hipMemsetAsync(stats, 0, 512 * 4, stream);
    hipMemsetAsync(cnt, 0, (size_t)N * 4, stream);
    prep_kernel<<<96, 256, 0, stream>>>(We0, W1_0, We1, W1_1, WeB0, W1B0, WeB1, W1B1);

    const int eb256 = (E + 255) / 256;

    // ----- CSR by dst (offs) + edge -> sorted-position map (inv) -----
    hist_kernel<<<eb256, 256, 0, stream>>>(ei, cnt, E);
    scan_kernel<<<1, 1024, 0, stream>>>(cnt, offs, cnt, N);  // cnt becomes cursor
    scatter_kernel<<<eb256, 256, 0, stream>>>(ei, cnt, inv, E);

    const int edge_blocks = (E + 63) / 64;
    const int n4_blocks   = (N + 3) / 4;

    // ----- layer 0 -----
    edge2_kernel<128><<<edge_blocks, 256, 0, stream>>>(
        x, ei, eattr, WeB0, be0, W1B0, inv, pbuf, E);
    gather_kernel<128><<<n4_blocks, 256, 0, stream>>>(
        pbuf, offs, x, W1_0, b1_0, tbuf, N);
    bnstats_kernel<<<256, 256, 0, stream>>>(tbuf, sum0, N * 64);
    bnfinal_kernel<<<1, 64, 0, stream>>>(sum0, g0, bb0, scsh0, 1.0f / N);
    mlp2_kernel<<<n4_blocks, 256, 0, stream>>>(tbuf, scsh0, W2_0, b2_0, y0, N, 1);

    // ----- layer 1 -----
    edge2_kernel<64><<<edge_blocks, 256, 0, stream>>>(
        y0, ei, eattr, WeB1, be1, W1B1, inv, pbuf, E);
    gather_kernel<64><<<n4_blocks, 256, 0, stream>>>(
        pbuf, offs, y0, W1_1, b1_1, tbuf, N);
    bnstats_kernel<<<256, 256, 0, stream>>>(tbuf, sum1, N * 64);
    bnfinal_kernel<<<1, 64, 0, stream>>>(sum1, g1, bb1, scsh1, 1.0f / N);
    mlp2_kernel<<<n4_blocks, 256, 0, stream>>>(tbuf, scsh1, W2_1, b2_1, out, N, 0);
}

// Round 5
// 1029.045 us; speedup vs baseline: 1.1699x; 1.0620x over previous
//
#include <hip/hip_runtime.h>
#include <hip/hip_bf16.h>

// ---------------------------------------------------------------------------
// GINE 2-layer GNN, MI355X (gfx950)  — round 5
//   t[n] = sum_{e: dst=n} relu(x[src]+ea_e)@W1^T  +  (x@W1^T + b1)
// Changes vs R4 (latency-bound: Mfma 4%, VALU 15%, HBM 21%, occ 53%):
//  1. Edge kernels hoist ALL x[src] gather loads into registers BEFORE
//     GEMM1 (compiler provably didn't: VGPR was 44). One latency burst.
//  2. L1 edge kernel drops GEMM2: aggregate m directly (linearity:
//     sum(m_e) @ W1^T == sum(m_e @ W1^T)), W1_1 applied per NODE in
//     gather1 (f32). Halves L1 edge MFMA + removes a serial chain.
//     L0 keeps edge-level GEMM2 (compresses 128->64 before pbuf).
// ---------------------------------------------------------------------------

typedef short short8 __attribute__((ext_vector_type(8)));
typedef float f32x4 __attribute__((ext_vector_type(4)));

__device__ __forceinline__ short f2bf(float x) {
    unsigned u = __float_as_uint(x);
    unsigned r = (u + 0x7fffu + ((u >> 16) & 1u)) >> 16;   // RTNE
    return (short)r;
}
__device__ __forceinline__ float bf2f(unsigned short u) {
    return __uint_as_float(((unsigned)u) << 16);
}

// ---------------------------------------------------------------------------
// Counting sort of edges by dst -> inv (edge id -> sorted pos), offs (CSR)
// ---------------------------------------------------------------------------
__global__ __launch_bounds__(256) void hist_kernel(
    const int* __restrict__ ei, int* __restrict__ cnt, int E)
{
    int e = blockIdx.x * 256 + threadIdx.x;
    if (e < E) atomicAdd(&cnt[ei[E + e]], 1);
}

__global__ __launch_bounds__(1024) void scan_kernel(
    const int* __restrict__ cnt, int* __restrict__ offs,
    int* __restrict__ cursor, int N)
{
    __shared__ int wsum[16];
    __shared__ int chunk_base;
    int tid = threadIdx.x;
    int lane = tid & 63, wid = tid >> 6;
    if (tid == 0) chunk_base = 0;
    __syncthreads();
    for (int start = 0; start < N; start += 1024) {
        int i = start + tid;
        int v = (i < N) ? cnt[i] : 0;
        int s = v;
#pragma unroll
        for (int d = 1; d < 64; d <<= 1) {
            int t = __shfl_up(s, d);
            if (lane >= d) s += t;
        }
        if (lane == 63) wsum[wid] = s;
        __syncthreads();
        int wbase = 0;
        for (int w = 0; w < wid; ++w) wbase += wsum[w];
        int excl = chunk_base + wbase + s - v;
        if (i < N) { offs[i] = excl; cursor[i] = excl; }
        int tot = 0;
        for (int w = 0; w < 16; ++w) tot += wsum[w];
        __syncthreads();
        if (tid == 0) chunk_base += tot;
        __syncthreads();
    }
    if (threadIdx.x == 0) offs[N] = chunk_base;
}

__global__ __launch_bounds__(256) void scatter_kernel(
    const int* __restrict__ ei, int* __restrict__ cursor,
    int* __restrict__ inv, int E)
{
    int e = blockIdx.x * 256 + threadIdx.x;
    if (e >= E) return;
    int d = ei[E + e];
    int pos = atomicAdd(&cursor[d], 1);
    inv[e] = pos;
}

// ---------------------------------------------------------------------------
// L0 edge kernel (DIN=128): wave = 16 edges.
// All global loads (A-frags, ei, inv, 32 x-gathers) hoisted to the top.
// GEMM1 -> relu epilogue -> bf16 LDS -> GEMM2 (p = m @ W1^T) ->
// store p bf16 at dst-sorted row inv[e].
// ---------------------------------------------------------------------------
template<int DIN>
__global__ __launch_bounds__(256) void edge2_kernel(
    const float*  __restrict__ x,      // [N][DIN]
    const int*    __restrict__ ei,     // [2][E] (src row used)
    const float*  __restrict__ eattr,  // [E][64]
    const short*  __restrict__ WeB,    // [DIN][64] bf16
    const float*  __restrict__ be,     // [DIN]
    const short*  __restrict__ W1B,    // [64][DIN] bf16
    const int*    __restrict__ inv,    // [E] edge -> sorted pos
    unsigned short* __restrict__ pbuf, // [E][64] bf16 (sorted rows)
    int E)
{
    constexpr int S = DIN + 8;             // shorts; rows 16B-aligned
    __shared__ short lds[4][16][S];
    const int wave = threadIdx.x >> 6;
    const int lane = threadIdx.x & 63;
    const int ebase = (blockIdx.x * 4 + wave) * 16;
    if (ebase >= E) return;
    const int g = lane >> 4;               // 0..3
    const int c = lane & 15;               // 0..15
    short* myl = &lds[wave][0][0];

    // ---- load burst: A-frags, src ids, sorted positions, x-gather ----
    int arow_e = ebase + c; if (arow_e >= E) arow_e = E - 1;
    const float* arow = eattr + (size_t)arow_e * 64 + g * 8;
    f32x4 a00 = *(const f32x4*)(arow);
    f32x4 a01 = *(const f32x4*)(arow + 4);
    f32x4 a10 = *(const f32x4*)(arow + 32);
    f32x4 a11 = *(const f32x4*)(arow + 36);

    int se[4], sp[4];
#pragma unroll
    for (int r = 0; r < 4; ++r) {
        int e = ebase + g * 4 + r;
        int es = (e < E) ? e : (E - 1);
        se[r] = ei[es];
        sp[r] = (e < E) ? inv[e] : -1;
    }

    constexpr int FC = DIN / 16;
    float xv[FC][4];
#pragma unroll
    for (int r = 0; r < 4; ++r) {
        const float* xrow = x + (size_t)se[r] * DIN + c;
#pragma unroll
        for (int fc = 0; fc < FC; ++fc)
            xv[fc][r] = xrow[fc * 16];
    }

    short8 afr[2];
    {
        short8 t;
        t[0] = f2bf(a00[0]); t[1] = f2bf(a00[1]); t[2] = f2bf(a00[2]); t[3] = f2bf(a00[3]);
        t[4] = f2bf(a01[0]); t[5] = f2bf(a01[1]); t[6] = f2bf(a01[2]); t[7] = f2bf(a01[3]);
        afr[0] = t;
        t[0] = f2bf(a10[0]); t[1] = f2bf(a10[1]); t[2] = f2bf(a10[2]); t[3] = f2bf(a10[3]);
        t[4] = f2bf(a11[0]); t[5] = f2bf(a11[1]); t[6] = f2bf(a11[2]); t[7] = f2bf(a11[3]);
        afr[1] = t;
    }

    // ---- GEMM1 + epilogue -> bf16 LDS ----
#pragma unroll
    for (int fc = 0; fc < FC; ++fc) {
        const short* brow = WeB + (size_t)(fc * 16 + c) * 64 + g * 8;
        short8 b0 = *(const short8*)(brow);
        short8 b1 = *(const short8*)(brow + 32);
        f32x4 acc = {0.f, 0.f, 0.f, 0.f};
        acc = __builtin_amdgcn_mfma_f32_16x16x32_bf16(afr[0], b0, acc, 0, 0, 0);
        acc = __builtin_amdgcn_mfma_f32_16x16x32_bf16(afr[1], b1, acc, 0, 0, 0);
        const int f = fc * 16 + c;
        const float bev = be[f];
#pragma unroll
        for (int r = 0; r < 4; ++r) {
            float m = fmaxf(acc[r] + bev + xv[fc][r], 0.f);
            myl[(g * 4 + r) * S + f] = f2bf(m);
        }
    }

    asm volatile("s_waitcnt lgkmcnt(0)" ::: "memory");
    __builtin_amdgcn_sched_barrier(0);

    // ---- A2 fragments straight from LDS ----
    constexpr int KK = DIN / 32;
    short8 a2[KK];
#pragma unroll
    for (int kk = 0; kk < KK; ++kk)
        a2[kk] = *(const short8*)(myl + c * S + kk * 32 + g * 8);

    // ---- GEMM2: p = m @ W1^T ; store bf16 at sorted row ----
#pragma unroll
    for (int cc = 0; cc < 4; ++cc) {
        f32x4 acc2 = {0.f, 0.f, 0.f, 0.f};
#pragma unroll
        for (int kk = 0; kk < KK; ++kk) {
            const short* brow = W1B + (size_t)(cc * 16 + c) * DIN + kk * 32 + g * 8;
            short8 b0 = *(const short8*)(brow);
            acc2 = __builtin_amdgcn_mfma_f32_16x16x32_bf16(a2[kk], b0, acc2, 0, 0, 0);
        }
#pragma unroll
        for (int r = 0; r < 4; ++r) {
            if (sp[r] >= 0)
                pbuf[(size_t)sp[r] * 64 + cc * 16 + c] = (unsigned short)f2bf(acc2[r]);
        }
    }
}

// ---------------------------------------------------------------------------
// L1 edge kernel (DIN=64, NO GEMM2): m = relu(y0[src] + eattr@We^T + be),
// transpose via LDS, store m bf16 at dst-sorted row. W1_1 applied later
// per node (linearity of the aggregation).
// ---------------------------------------------------------------------------
__global__ __launch_bounds__(256) void edge1_kernel(
    const float*  __restrict__ x,      // [N][64] (y0)
    const int*    __restrict__ ei,     // [2][E]
    const float*  __restrict__ eattr,  // [E][64]
    const short*  __restrict__ WeB,    // [64][64] bf16
    const float*  __restrict__ be,     // [64]
    const int*    __restrict__ inv,    // [E]
    unsigned short* __restrict__ pbuf, // [E][64] bf16 m (sorted rows)
    int E)
{
    constexpr int S = 72;
    __shared__ short lds[4][16][S];
    const int wave = threadIdx.x >> 6;
    const int lane = threadIdx.x & 63;
    const int ebase = (blockIdx.x * 4 + wave) * 16;
    if (ebase >= E) return;
    const int g = lane >> 4;
    const int c = lane & 15;
    short* myl = &lds[wave][0][0];

    // ---- load burst ----
    int arow_e = ebase + c; if (arow_e >= E) arow_e = E - 1;
    const float* arow = eattr + (size_t)arow_e * 64 + g * 8;
    f32x4 a00 = *(const f32x4*)(arow);
    f32x4 a01 = *(const f32x4*)(arow + 4);
    f32x4 a10 = *(const f32x4*)(arow + 32);
    f32x4 a11 = *(const f32x4*)(arow + 36);

    int se[4];
#pragma unroll
    for (int r = 0; r < 4; ++r) {
        int e = ebase + g * 4 + r;
        se[r] = ei[(e < E) ? e : (E - 1)];
    }
    int ec = ebase + c;
    int spc = (ec < E) ? inv[ec] : -1;

    float xv[4][4];   // [fc][r]
#pragma unroll
    for (int r = 0; r < 4; ++r) {
        const float* xrow = x + (size_t)se[r] * 64 + c;
#pragma unroll
        for (int fc = 0; fc < 4; ++fc)
            xv[fc][r] = xrow[fc * 16];
    }

    short8 afr[2];
    {
        short8 t;
        t[0] = f2bf(a00[0]); t[1] = f2bf(a00[1]); t[2] = f2bf(a00[2]); t[3] = f2bf(a00[3]);
        t[4] = f2bf(a01[0]); t[5] = f2bf(a01[1]); t[6] = f2bf(a01[2]); t[7] = f2bf(a01[3]);
        afr[0] = t;
        t[0] = f2bf(a10[0]); t[1] = f2bf(a10[1]); t[2] = f2bf(a10[2]); t[3] = f2bf(a10[3]);
        t[4] = f2bf(a11[0]); t[5] = f2bf(a11[1]); t[6] = f2bf(a11[2]); t[7] = f2bf(a11[3]);
        afr[1] = t;
    }

    // ---- GEMM1 + epilogue -> bf16 LDS ----
#pragma unroll
    for (int fc = 0; fc < 4; ++fc) {
        const short* brow = WeB + (size_t)(fc * 16 + c) * 64 + g * 8;
        short8 b0 = *(const short8*)(brow);
        short8 b1 = *(const short8*)(brow + 32);
        f32x4 acc = {0.f, 0.f, 0.f, 0.f};
        acc = __builtin_amdgcn_mfma_f32_16x16x32_bf16(afr[0], b0, acc, 0, 0, 0);
        acc = __builtin_amdgcn_mfma_f32_16x16x32_bf16(afr[1], b1, acc, 0, 0, 0);
        const int f = fc * 16 + c;
        const float bev = be[f];
#pragma unroll
        for (int r = 0; r < 4; ++r) {
            float m = fmaxf(acc[r] + bev + xv[fc][r], 0.f);
            myl[(g * 4 + r) * S + f] = f2bf(m);
        }
    }

    asm volatile("s_waitcnt lgkmcnt(0)" ::: "memory");
    __builtin_amdgcn_sched_barrier(0);

    // ---- coalesced-row store: lane (g,c) writes edge c, feats g*8 & 32+g*8
    short8 v0 = *(const short8*)(myl + c * S + g * 8);
    short8 v1 = *(const short8*)(myl + c * S + 32 + g * 8);
    if (spc >= 0) {
        *(short8*)(pbuf + (size_t)spc * 64 + g * 8) = v0;
        *(short8*)(pbuf + (size_t)spc * 64 + 32 + g * 8) = v1;
    }
}

// ---------------------------------------------------------------------------
// L0 gather (fused dense xw1): wave per node, lane = out feature f.
//   t[n][f] = b1[f] + x[n].W1[f] + sum_i pbuf[i][f]   (contiguous rows)
// ---------------------------------------------------------------------------
template<int DIN>
__global__ __launch_bounds__(256) void gather_kernel(
    const unsigned short* __restrict__ pbuf,
    const int* __restrict__ offs,
    const float* __restrict__ x, const float* __restrict__ W1,
    const float* __restrict__ b1, float* __restrict__ t, int N)
{
    int wid = threadIdx.x >> 6, lane = threadIdx.x & 63;
    int n = blockIdx.x * 4 + wid;
    if (n >= N) return;

    const f32x4* xr = (const f32x4*)(x + (size_t)n * DIN);
    const f32x4* wr = (const f32x4*)(W1 + (size_t)lane * DIN);
    float acc = b1[lane];
#pragma unroll
    for (int k = 0; k < DIN / 4; ++k) {
        f32x4 xx = xr[k], w = wr[k];
        acc += xx[0] * w[0] + xx[1] * w[1] + xx[2] * w[2] + xx[3] * w[3];
    }

    int i0 = offs[n], i1 = offs[n + 1];
    const unsigned short* p = pbuf + (size_t)i0 * 64 + lane;
    int cnt = i1 - i0;
    int i = 0;
    for (; i + 3 < cnt; i += 4) {
        acc += bf2f(p[0]) + bf2f(p[64]) + bf2f(p[128]) + bf2f(p[192]);
        p += 256;
    }
    for (; i < cnt; ++i) { acc += bf2f(p[0]); p += 64; }
    t[(size_t)n * 64 + lane] = acc;
}

// ---------------------------------------------------------------------------
// L1 gather + node-level W1 apply (f32 exact):
//   s[k] = y0[n][k] + sum_i pbuf[i][k]      (LDS row per wave)
//   t[n][f] = b1[f] + sum_k s[k] * W1[f][k]
// ---------------------------------------------------------------------------
__global__ __launch_bounds__(256) void gather1_kernel(
    const unsigned short* __restrict__ pbuf,
    const int* __restrict__ offs,
    const float* __restrict__ y0, const float* __restrict__ W1,
    const float* __restrict__ b1, float* __restrict__ t, int N)
{
    __shared__ __align__(16) float sm[4][64];
    int wid = threadIdx.x >> 6, lane = threadIdx.x & 63;
    int n = blockIdx.x * 4 + wid;
    if (n >= N) return;

    int i0 = offs[n], i1 = offs[n + 1];
    float s = y0[(size_t)n * 64 + lane];
    const unsigned short* p = pbuf + (size_t)i0 * 64 + lane;
    int cnt = i1 - i0;
    int i = 0;
    for (; i + 3 < cnt; i += 4) {
        s += bf2f(p[0]) + bf2f(p[64]) + bf2f(p[128]) + bf2f(p[192]);
        p += 256;
    }
    for (; i < cnt; ++i) { s += bf2f(p[0]); p += 64; }
    sm[wid][lane] = s;

    asm volatile("s_waitcnt lgkmcnt(0)" ::: "memory");
    __builtin_amdgcn_sched_barrier(0);

    const f32x4* wr = (const f32x4*)(W1 + (size_t)lane * 64);
    const f32x4* sr = (const f32x4*)(sm[wid]);
    float acc = b1[lane];
#pragma unroll
    for (int kk = 0; kk < 16; ++kk) {
        f32x4 w = wr[kk], ss = sr[kk];
        acc += ss[0] * w[0] + ss[1] * w[1] + ss[2] * w[2] + ss[3] * w[3];
    }
    t[(size_t)n * 64 + lane] = acc;
}

// ---------------------------------------------------------------------------
// BN stats + final
// ---------------------------------------------------------------------------
__global__ __launch_bounds__(256) void bnstats_kernel(
    const float* __restrict__ t, float* __restrict__ sums, int total)
{
    int tid = threadIdx.x;
    float s = 0.f, s2 = 0.f;
    for (int i = blockIdx.x * 256 + tid; i < total; i += gridDim.x * 256) {
        float v = t[i];
        s += v; s2 += v * v;
    }
    __shared__ float ls[256], ls2[256];
    ls[tid] = s; ls2[tid] = s2;
    __syncthreads();
    if (tid < 64) {
        s  = ls[tid]  + ls[tid + 64]  + ls[tid + 128]  + ls[tid + 192];
        s2 = ls2[tid] + ls2[tid + 64] + ls2[tid + 128] + ls2[tid + 192];
        atomicAdd(&sums[tid], s);
        atomicAdd(&sums[64 + tid], s2);
    }
}

__global__ void bnfinal_kernel(const float* __restrict__ sums,
                               const float* __restrict__ g,
                               const float* __restrict__ bb,
                               float* __restrict__ scsh, float invN)
{
    int f = threadIdx.x;  // 64 threads
    float mean = sums[f] * invN;
    float var  = sums[64 + f] * invN - mean * mean;
    float sc = g[f] * rsqrtf(var + 1e-5f);
    scsh[f] = sc;
    scsh[64 + f] = bb[f] - mean * sc;
}

// ---------------------------------------------------------------------------
// mlp2: h = relu(t*scale+shift); out = h @ W2^T + b2 (+optional relu)
// ---------------------------------------------------------------------------
__global__ __launch_bounds__(256) void mlp2_kernel(
    const float* __restrict__ t, const float* __restrict__ scsh,
    const float* __restrict__ W2, const float* __restrict__ b2,
    float* __restrict__ out, int N, int relu_out)
{
    __shared__ __align__(16) float hs[4][64];
    int tid = threadIdx.x;
    int nl = tid >> 6, k = tid & 63;
    int n = blockIdx.x * 4 + nl;
    float h = 0.f;
    if (n < N) h = fmaxf(t[(size_t)n * 64 + k] * scsh[k] + scsh[64 + k], 0.f);
    hs[nl][k] = h;
    __syncthreads();
    if (n >= N) return;
    const int f = k;
    const f32x4* wr = (const f32x4*)(W2 + (size_t)f * 64);
    const f32x4* hr = (const f32x4*)(hs[nl]);
    float acc = b2[f];
#pragma unroll
    for (int kk = 0; kk < 16; ++kk) {
        f32x4 w = wr[kk], hh = hr[kk];
        acc += hh[0] * w[0] + hh[1] * w[1] + hh[2] * w[2] + hh[3] * w[3];
    }
    if (relu_out) acc = fmaxf(acc, 0.f);
    out[(size_t)n * 64 + f] = acc;
}

// ---------------------------------------------------------------------------
// Weight prep: f32 -> bf16 (WeB0 128x64, W1B0 64x128, WeB1 64x64)
// ---------------------------------------------------------------------------
__global__ __launch_bounds__(256) void prep_kernel(
    const float* __restrict__ We0, const float* __restrict__ W1_0,
    const float* __restrict__ We1,
    short* __restrict__ WeB0, short* __restrict__ W1B0,
    short* __restrict__ WeB1)
{
    int i = blockIdx.x * 256 + threadIdx.x;
    if (i < 128 * 64) WeB0[i] = f2bf(We0[i]);
    if (i < 64 * 128) W1B0[i] = f2bf(W1_0[i]);
    if (i < 64 * 64)  WeB1[i] = f2bf(We1[i]);
}

extern "C" void kernel_launch(void* const* d_in, const int* in_sizes, int n_in,
                              void* d_out, int out_size, void* d_ws, size_t ws_size,
                              hipStream_t stream)
{
    (void)n_in; (void)out_size; (void)ws_size;
    const float* x     = (const float*)d_in[0];
    const int*   ei    = (const int*)d_in[1];
    const float* eattr = (const float*)d_in[2];
    const float* We0   = (const float*)d_in[3];
    const float* be0   = (const float*)d_in[4];
    const float* W1_0  = (const float*)d_in[5];
    const float* b1_0  = (const float*)d_in[6];
    const float* g0    = (const float*)d_in[7];
    const float* bb0   = (const float*)d_in[8];
    const float* W2_0  = (const float*)d_in[9];
    const float* b2_0  = (const float*)d_in[10];
    const float* We1   = (const float*)d_in[11];
    const float* be1   = (const float*)d_in[12];
    const float* W1_1  = (const float*)d_in[13];
    const float* b1_1  = (const float*)d_in[14];
    const float* g1    = (const float*)d_in[15];
    const float* bb1   = (const float*)d_in[16];
    const float* W2_1  = (const float*)d_in[17];
    const float* b2_1  = (const float*)d_in[18];
    float* out = (float*)d_out;

    const int N = in_sizes[0] / 128;   // 50000
    const int E = in_sizes[2] / 64;    // 800000

    char* ws = (char*)d_ws;
    size_t o = 0;
    auto alloc = [&](size_t bytes) { char* p = ws + o; o = (o + bytes + 255) & ~(size_t)255; return p; };
    unsigned short* pbuf = (unsigned short*)alloc((size_t)E * 64 * 2);
    float* tbuf   = (float*)alloc((size_t)N * 64 * 4);
    float* y0     = (float*)alloc((size_t)N * 64 * 4);
    short* WeB0   = (short*)alloc(128 * 64 * 2);
    short* W1B0   = (short*)alloc(64 * 128 * 2);
    short* WeB1   = (short*)alloc(64 * 64 * 2);
    float* stats  = (float*)alloc(512 * 4);
    int*   cnt    = (int*)alloc((size_t)N * 4);
    int*   offs   = (int*)alloc((size_t)(N + 1) * 4);
    int*   inv    = (int*)alloc((size_t)E * 4);
    float* sum0  = stats;          // [128] sum+sumsq
    float* scsh0 = stats + 128;    // [128] scale+shift
    float* sum1  = stats + 256;
    float* scsh1 = stats + 384;

    hipMemsetAsync(stats, 0, 512 * 4, stream);
    hipMemsetAsync(cnt, 0, (size_t)N * 4, stream);
    prep_kernel<<<64, 256, 0, stream>>>(We0, W1_0, We1, WeB0, W1B0, WeB1);

    const int eb256 = (E + 255) / 256;

    // ----- CSR by dst (offs) + edge -> sorted-position map (inv) -----
    hist_kernel<<<eb256, 256, 0, stream>>>(ei, cnt, E);
    scan_kernel<<<1, 1024, 0, stream>>>(cnt, offs, cnt, N);  // cnt becomes cursor
    scatter_kernel<<<eb256, 256, 0, stream>>>(ei, cnt, inv, E);

    const int edge_blocks = (E + 63) / 64;
    const int n4_blocks   = (N + 3) / 4;

    // ----- layer 0 -----
    edge2_kernel<128><<<edge_blocks, 256, 0, stream>>>(
        x, ei, eattr, WeB0, be0, W1B0, inv, pbuf, E);
    gather_kernel<128><<<n4_blocks, 256, 0, stream>>>(
        pbuf, offs, x, W1_0, b1_0, tbuf, N);
    bnstats_kernel<<<256, 256, 0, stream>>>(tbuf, sum0, N * 64);
    bnfinal_kernel<<<1, 64, 0, stream>>>(sum0, g0, bb0, scsh0, 1.0f / N);
    mlp2_kernel<<<n4_blocks, 256, 0, stream>>>(tbuf, scsh0, W2_0, b2_0, y0, N, 1);

    // ----- layer 1 -----
    edge1_kernel<<<edge_blocks, 256, 0, stream>>>(
        y0, ei, eattr, WeB1, be1, inv, pbuf, E);
    gather1_kernel<<<n4_blocks, 256, 0, stream>>>(
        pbuf, offs, y0, W1_1, b1_1, tbuf, N);
    bnstats_kernel<<<256, 256, 0, stream>>>(tbuf, sum1, N * 64);
    bnfinal_kernel<<<1, 64, 0, stream>>>(sum1, g1, bb1, scsh1, 1.0f / N);
    mlp2_kernel<<<n4_blocks, 256, 0, stream>>>(tbuf, scsh1, W2_1, b2_1, out, N, 0);
}